// Round 1
// baseline (586.546 us; speedup 1.0000x reference)
//
#include <hip/hip_runtime.h>
#include <hip/hip_bf16.h>
#include <stdint.h>

#define IN_DIM 4096
#define OUT_DIM 4096
#define M_ROWS 8192   // 4 * 2048

typedef __attribute__((ext_vector_type(8))) short s16x8;
typedef __attribute__((ext_vector_type(4))) float f32x4;

__device__ __forceinline__ unsigned short f2bf(float f) {
  uint32_t u = __float_as_uint(f);
  uint32_t r = (u + 0x7fffu + ((u >> 16) & 1u)) >> 16;  // RNE
  return (unsigned short)r;
}

__device__ __forceinline__ void async16(void* lds, const void* g) {
  __builtin_amdgcn_global_load_lds(
      (const __attribute__((address_space(1))) unsigned int*)g,
      (__attribute__((address_space(3))) unsigned int*)lds, 16, 0, 0);
}

// ---------------- Stage 1: xh = fwht(x * SU), one row per block ----------------
__global__ void fwht_x_kernel(const float* __restrict__ x, const float* __restrict__ SU,
                              float* __restrict__ xh) {
  __shared__ float s[4096];
  const int row = blockIdx.x;
  const int tid = threadIdx.x;
  const float4* xr  = (const float4*)(x + (size_t)row * IN_DIM);
  const float4* su4 = (const float4*)SU;
#pragma unroll
  for (int j = 0; j < 4; ++j) {
    int i4 = j * 256 + tid;
    float4 v = xr[i4], sv = su4[i4];
    s[i4 * 4 + 0] = v.x * sv.x;
    s[i4 * 4 + 1] = v.y * sv.y;
    s[i4 * 4 + 2] = v.z * sv.z;
    s[i4 * 4 + 3] = v.w * sv.w;
  }
  for (int h = 1; h < 4096; h <<= 1) {
    __syncthreads();
#pragma unroll
    for (int jj = 0; jj < 8; ++jj) {
      int p = jj * 256 + tid;                    // 0..2047 pair index
      int r = p & (h - 1);
      int i0 = ((p & ~(h - 1)) << 1) | r;
      float a = s[i0], b = s[i0 + h];
      s[i0] = a + b;
      s[i0 + h] = a - b;
    }
  }
  __syncthreads();
  float4* o4 = (float4*)(xh + (size_t)row * IN_DIM);
#pragma unroll
  for (int j = 0; j < 4; ++j) {
    int i4 = j * 256 + tid;
    float4 v;
    v.x = s[i4 * 4 + 0] * 0.015625f;  // 1/sqrt(4096) = 1/64
    v.y = s[i4 * 4 + 1] * 0.015625f;
    v.z = s[i4 * 4 + 2] * 0.015625f;
    v.w = s[i4 * 4 + 3] * 0.015625f;
    o4[i4] = v;
  }
}

// ---------------- Stage 2: per-channel min/max (two-stage) ----------------
__global__ void minmax_part_kernel(const float* __restrict__ xh,
                                   float* __restrict__ pmin, float* __restrict__ pmax) {
  const int rc = blockIdx.x >> 4;   // 0..31 row-chunk of 256 rows
  const int cb = blockIdx.x & 15;   // 0..15 channel block of 256
  const int ch = cb * 256 + threadIdx.x;
  float mn = 3.4e38f, mx = -3.4e38f;
  const float* base = xh + (size_t)rc * 256 * IN_DIM + ch;
  for (int r = 0; r < 256; ++r) {
    float v = base[(size_t)r * IN_DIM];
    mn = fminf(mn, v);
    mx = fmaxf(mx, v);
  }
  pmin[rc * IN_DIM + ch] = mn;
  pmax[rc * IN_DIM + ch] = mx;
}

__global__ void minmax_fin_kernel(const float* __restrict__ pmin, const float* __restrict__ pmax,
                                  float* __restrict__ scale, float* __restrict__ zero) {
  int ch = blockIdx.x * 256 + threadIdx.x;
  float mn = 3.4e38f, mx = -3.4e38f;
  for (int rc = 0; rc < 32; ++rc) {
    mn = fminf(mn, pmin[rc * IN_DIM + ch]);
    mx = fmaxf(mx, pmax[rc * IN_DIM + ch]);
  }
  float sc = fmaxf((mx - mn) / 255.0f, 1e-8f);
  float zp = rintf(-mn / sc);  // rintf = half-to-even = jnp.round
  scale[ch] = sc;
  zero[ch] = zp;
}

// ---------------- Stage 3: fake-quant + bf16 cast ----------------
__global__ void quant_kernel(const float* __restrict__ xh, const float* __restrict__ scale,
                             const float* __restrict__ zero, unsigned short* __restrict__ xq) {
  const int total4 = M_ROWS * IN_DIM / 4;
  for (int i4 = blockIdx.x * blockDim.x + threadIdx.x; i4 < total4;
       i4 += gridDim.x * blockDim.x) {
    int c4 = i4 & (IN_DIM / 4 - 1);
    float4 v  = ((const float4*)xh)[i4];
    float4 sc = ((const float4*)scale)[c4];
    float4 zp = ((const float4*)zero)[c4];
    float q0 = fminf(fmaxf(rintf(v.x / sc.x) + zp.x, 0.f), 255.f);
    float q1 = fminf(fmaxf(rintf(v.y / sc.y) + zp.y, 0.f), 255.f);
    float q2 = fminf(fmaxf(rintf(v.z / sc.z) + zp.z, 0.f), 255.f);
    float q3 = fminf(fmaxf(rintf(v.w / sc.w) + zp.w, 0.f), 255.f);
    ushort4 o;
    o.x = f2bf((q0 - zp.x) * sc.x);
    o.y = f2bf((q1 - zp.y) * sc.y);
    o.z = f2bf((q2 - zp.z) * sc.z);
    o.w = f2bf((q3 - zp.w) * sc.w);
    ((ushort4*)xq)[i4] = o;
  }
}

// ---------------- Stage 4: trellis decode (8 codes per 16-bit word) ----------------
__global__ void decode_kernel(const int* __restrict__ trellis, float* __restrict__ w) {
  const int nwords = (OUT_DIM * IN_DIM / 256) * 32;  // 2097152
  int t = blockIdx.x * blockDim.x + threadIdx.x;
  if (t >= nwords) return;
  int word = trellis[t];
  const float g = 0.44721359549995793f;  // 1/sqrt(5)
  float4 lo, hi;
  lo.x = (float)(2 * ((word >> 14) & 3) - 3) * g;
  lo.y = (float)(2 * ((word >> 12) & 3) - 3) * g;
  lo.z = (float)(2 * ((word >> 10) & 3) - 3) * g;
  lo.w = (float)(2 * ((word >> 8)  & 3) - 3) * g;
  hi.x = (float)(2 * ((word >> 6)  & 3) - 3) * g;
  hi.y = (float)(2 * ((word >> 4)  & 3) - 3) * g;
  hi.z = (float)(2 * ((word >> 2)  & 3) - 3) * g;
  hi.w = (float)(2 * ((word >> 0)  & 3) - 3) * g;
  float4* dst = (float4*)(w + (size_t)t * 8);
  dst[0] = lo;
  dst[1] = hi;
}

// ---------------- Stage 5: FWHT along OUT = (H64 x H64), two passes ----------------
// Pass A: bits 0..5 of o (o = ohi*64 + olo, transform over olo)
__global__ void fwht_w_inner(float* __restrict__ w) {
  __shared__ float t[64][65];
  const int ohi = blockIdx.x >> 6;
  const int it  = blockIdx.x & 63;
  const int tid = threadIdx.x;
#pragma unroll
  for (int j = 0; j < 16; ++j) {
    int e = j * 256 + tid;
    int r = e >> 6, c = e & 63;
    t[r][c] = w[((size_t)(ohi * 64 + r)) * IN_DIM + it * 64 + c];
  }
  for (int h = 1; h < 64; h <<= 1) {
    __syncthreads();
#pragma unroll
    for (int j = 0; j < 8; ++j) {
      int p = j * 256 + tid;   // 0..2047
      int c = p & 63, q = p >> 6;
      int rr = q & (h - 1);
      int i0 = ((q & ~(h - 1)) << 1) | rr;
      float a = t[i0][c], b = t[i0 + h][c];
      t[i0][c] = a + b;
      t[i0 + h][c] = a - b;
    }
  }
  __syncthreads();
#pragma unroll
  for (int j = 0; j < 16; ++j) {
    int e = j * 256 + tid;
    int r = e >> 6, c = e & 63;
    w[((size_t)(ohi * 64 + r)) * IN_DIM + it * 64 + c] = t[r][c];
  }
}

// Pass B: bits 6..11 (transform over ohi) + 1/64 norm + SV + group scales + bf16
__global__ void fwht_w_outer(const float* __restrict__ w, const float* __restrict__ SV,
                             const float* __restrict__ wscale, unsigned short* __restrict__ wq) {
  __shared__ float t[64][65];
  const int olo = blockIdx.x >> 6;
  const int it  = blockIdx.x & 63;
  const int tid = threadIdx.x;
#pragma unroll
  for (int j = 0; j < 16; ++j) {
    int e = j * 256 + tid;
    int r = e >> 6, c = e & 63;
    t[r][c] = w[((size_t)(r * 64 + olo)) * IN_DIM + it * 64 + c];
  }
  for (int h = 1; h < 64; h <<= 1) {
    __syncthreads();
#pragma unroll
    for (int j = 0; j < 8; ++j) {
      int p = j * 256 + tid;
      int c = p & 63, q = p >> 6;
      int rr = q & (h - 1);
      int i0 = ((q & ~(h - 1)) << 1) | rr;
      float a = t[i0][c], b = t[i0 + h][c];
      t[i0][c] = a + b;
      t[i0 + h][c] = a - b;
    }
  }
  __syncthreads();
#pragma unroll
  for (int j = 0; j < 16; ++j) {
    int e = j * 256 + tid;
    int r = e >> 6, c = e & 63;
    int o = r * 64 + olo;
    int i = it * 64 + c;
    float val = t[r][c] * 0.015625f * SV[o] * wscale[(o << 4) + (i >> 8)];
    wq[(size_t)o * IN_DIM + i] = f2bf(val);
  }
}

// ---------------- Stage 6: bf16 GEMM, C[m,o] = sum_k A[m,k]*B[o,k] ----------------
// m97 structure: 128x128 tile, BK=32, 4 waves (2x2), global_load_lds width 16.
__global__ __launch_bounds__(256) void gemm_kernel(const unsigned short* __restrict__ A,
                                                   const unsigned short* __restrict__ B,
                                                   float* __restrict__ C) {
  __shared__ unsigned short lA[128 * 32];
  __shared__ unsigned short lB[128 * 32];
  const int t = threadIdx.x;
  const int lane = t & 63;
  const int wave = t >> 6;
  const int wm = wave >> 1, wn = wave & 1;
  const int nbx = OUT_DIM / 128;  // 32
  const int bm = blockIdx.x / nbx, bn = blockIdx.x % nbx;
  const int gm0 = bm * 128, gn0 = bn * 128;

  f32x4 acc[4][4] = {};
  const int fr = lane & 15;
  const int kq = (lane >> 4) * 8;

  const int idx0 = t, idx1 = 256 + t;
  const int r0 = idx0 >> 2, c0 = (idx0 & 3) * 8;
  const int r1 = idx1 >> 2, c1 = (idx1 & 3) * 8;

  for (int k0 = 0; k0 < IN_DIM; k0 += 32) {
    __syncthreads();
    async16(&lA[idx0 * 8], A + (size_t)(gm0 + r0) * IN_DIM + k0 + c0);
    async16(&lA[idx1 * 8], A + (size_t)(gm0 + r1) * IN_DIM + k0 + c1);
    async16(&lB[idx0 * 8], B + (size_t)(gn0 + r0) * IN_DIM + k0 + c0);
    async16(&lB[idx1 * 8], B + (size_t)(gn0 + r1) * IN_DIM + k0 + c1);
    __syncthreads();

    s16x8 af[4], bf[4];
#pragma unroll
    for (int m = 0; m < 4; ++m)
      af[m] = *(const s16x8*)&lA[(wm * 64 + m * 16 + fr) * 32 + kq];
#pragma unroll
    for (int n = 0; n < 4; ++n)
      bf[n] = *(const s16x8*)&lB[(wn * 64 + n * 16 + fr) * 32 + kq];
#pragma unroll
    for (int m = 0; m < 4; ++m)
#pragma unroll
      for (int n = 0; n < 4; ++n)
        acc[m][n] = __builtin_amdgcn_mfma_f32_16x16x32_bf16(af[m], bf[n], acc[m][n], 0, 0, 0);
  }

  const int orow = (lane >> 4) * 4;
#pragma unroll
  for (int m = 0; m < 4; ++m) {
#pragma unroll
    for (int n = 0; n < 4; ++n) {
      int col = gn0 + wn * 64 + n * 16 + fr;
#pragma unroll
      for (int r = 0; r < 4; ++r) {
        int row = gm0 + wm * 64 + m * 16 + orow + r;
        C[(size_t)row * OUT_DIM + col] = acc[m][n][r];
      }
    }
  }
}

// ---------------- launch ----------------
extern "C" void kernel_launch(void* const* d_in, const int* in_sizes, int n_in,
                              void* d_out, int out_size, void* d_ws, size_t ws_size,
                              hipStream_t stream) {
  const float* x      = (const float*)d_in[0];
  const float* SU     = (const float*)d_in[1];
  const float* SV     = (const float*)d_in[2];
  const float* wscale = (const float*)d_in[3];
  const int* trellis  = (const int*)d_in[4];
  float* out = (float*)d_out;

  // ws layout (96 MiB total):
  //   xq bf16 [0, 64Mi)
  //   wq bf16 [64Mi, 96Mi)  -- min/max partials + scale/zero aliased here (consumed
  //                            before wq is produced)
  char* ws = (char*)d_ws;
  unsigned short* xq = (unsigned short*)ws;
  unsigned short* wq = (unsigned short*)(ws + (size_t)67108864);
  float* pmin  = (float*)(ws + (size_t)67108864);            // 512 KiB
  float* pmax  = (float*)(ws + (size_t)67108864 + 524288);   // 512 KiB
  float* scale = (float*)(ws + (size_t)67108864 + 1048576);  // 16 KiB
  float* zero  = (float*)(ws + (size_t)67108864 + 1064960);  // 16 KiB

  float* xh   = out;  // reuse d_out (128 MiB) as xh scratch
  float* wdec = out;  // then (after quant consumes xh) as decoded-W scratch (64 MiB)

  hipLaunchKernelGGL(fwht_x_kernel, dim3(M_ROWS), dim3(256), 0, stream, x, SU, xh);
  hipLaunchKernelGGL(minmax_part_kernel, dim3(512), dim3(256), 0, stream, xh, pmin, pmax);
  hipLaunchKernelGGL(minmax_fin_kernel, dim3(16), dim3(256), 0, stream, pmin, pmax, scale, zero);
  hipLaunchKernelGGL(quant_kernel, dim3(2048), dim3(256), 0, stream, xh, scale, zero, xq);
  hipLaunchKernelGGL(decode_kernel, dim3(8192), dim3(256), 0, stream, trellis, wdec);
  hipLaunchKernelGGL(fwht_w_inner, dim3(4096), dim3(256), 0, stream, wdec);
  hipLaunchKernelGGL(fwht_w_outer, dim3(4096), dim3(256), 0, stream, wdec, SV, wscale, wq);
  hipLaunchKernelGGL(gemm_kernel, dim3((M_ROWS / 128) * (OUT_DIM / 128)), dim3(256), 0, stream,
                     xq, wq, out);
}

// Round 2
// 435.328 us; speedup vs baseline: 1.3474x; 1.3474x over previous
//
#include <hip/hip_runtime.h>
#include <hip/hip_bf16.h>
#include <stdint.h>

#define IN_DIM 4096
#define OUT_DIM 4096
#define M_ROWS 8192   // 4 * 2048

typedef __attribute__((ext_vector_type(8))) short s16x8;
typedef __attribute__((ext_vector_type(4))) float f32x4;

__device__ __forceinline__ unsigned short f2bf(float f) {
  uint32_t u = __float_as_uint(f);
  uint32_t r = (u + 0x7fffu + ((u >> 16) & 1u)) >> 16;  // RNE
  return (unsigned short)r;
}

__device__ __forceinline__ void async16(void* lds, const void* g) {
  __builtin_amdgcn_global_load_lds(
      (const __attribute__((address_space(1))) unsigned int*)g,
      (__attribute__((address_space(3))) unsigned int*)lds, 16, 0, 0);
}

#define FENCE asm volatile("" ::: "memory")

// ---------------- Stage 1: xh = fwht(x * SU), one row per block ----------------
__global__ void fwht_x_kernel(const float* __restrict__ x, const float* __restrict__ SU,
                              float* __restrict__ xh) {
  __shared__ float s[4096];
  const int row = blockIdx.x;
  const int tid = threadIdx.x;
  const float4* xr  = (const float4*)(x + (size_t)row * IN_DIM);
  const float4* su4 = (const float4*)SU;
#pragma unroll
  for (int j = 0; j < 4; ++j) {
    int i4 = j * 256 + tid;
    float4 v = xr[i4], sv = su4[i4];
    s[i4 * 4 + 0] = v.x * sv.x;
    s[i4 * 4 + 1] = v.y * sv.y;
    s[i4 * 4 + 2] = v.z * sv.z;
    s[i4 * 4 + 3] = v.w * sv.w;
  }
  for (int h = 1; h < 4096; h <<= 1) {
    __syncthreads();
#pragma unroll
    for (int jj = 0; jj < 8; ++jj) {
      int p = jj * 256 + tid;                    // 0..2047 pair index
      int r = p & (h - 1);
      int i0 = ((p & ~(h - 1)) << 1) | r;
      float a = s[i0], b = s[i0 + h];
      s[i0] = a + b;
      s[i0 + h] = a - b;
    }
  }
  __syncthreads();
  float4* o4 = (float4*)(xh + (size_t)row * IN_DIM);
#pragma unroll
  for (int j = 0; j < 4; ++j) {
    int i4 = j * 256 + tid;
    float4 v;
    v.x = s[i4 * 4 + 0] * 0.015625f;  // 1/sqrt(4096) = 1/64
    v.y = s[i4 * 4 + 1] * 0.015625f;
    v.z = s[i4 * 4 + 2] * 0.015625f;
    v.w = s[i4 * 4 + 3] * 0.015625f;
    o4[i4] = v;
  }
}

// ---------------- Stage 2: per-channel min/max (two-stage) ----------------
__global__ void minmax_part_kernel(const float* __restrict__ xh,
                                   float* __restrict__ pmin, float* __restrict__ pmax) {
  const int rc = blockIdx.x >> 4;   // 0..31 row-chunk of 256 rows
  const int cb = blockIdx.x & 15;   // 0..15 channel block of 256
  const int ch = cb * 256 + threadIdx.x;
  float mn = 3.4e38f, mx = -3.4e38f;
  const float* base = xh + (size_t)rc * 256 * IN_DIM + ch;
  for (int r = 0; r < 256; ++r) {
    float v = base[(size_t)r * IN_DIM];
    mn = fminf(mn, v);
    mx = fmaxf(mx, v);
  }
  pmin[rc * IN_DIM + ch] = mn;
  pmax[rc * IN_DIM + ch] = mx;
}

__global__ void minmax_fin_kernel(const float* __restrict__ pmin, const float* __restrict__ pmax,
                                  float* __restrict__ scale, float* __restrict__ zero) {
  int ch = blockIdx.x * 256 + threadIdx.x;
  float mn = 3.4e38f, mx = -3.4e38f;
  for (int rc = 0; rc < 32; ++rc) {
    mn = fminf(mn, pmin[rc * IN_DIM + ch]);
    mx = fmaxf(mx, pmax[rc * IN_DIM + ch]);
  }
  float sc = fmaxf((mx - mn) / 255.0f, 1e-8f);
  float zp = rintf(-mn / sc);  // rintf = half-to-even = jnp.round
  scale[ch] = sc;
  zero[ch] = zp;
}

// ---------------- Stage 3: fake-quant + bf16 cast ----------------
__global__ void quant_kernel(const float* __restrict__ xh, const float* __restrict__ scale,
                             const float* __restrict__ zero, unsigned short* __restrict__ xq) {
  const int total4 = M_ROWS * IN_DIM / 4;
  for (int i4 = blockIdx.x * blockDim.x + threadIdx.x; i4 < total4;
       i4 += gridDim.x * blockDim.x) {
    int c4 = i4 & (IN_DIM / 4 - 1);
    float4 v  = ((const float4*)xh)[i4];
    float4 sc = ((const float4*)scale)[c4];
    float4 zp = ((const float4*)zero)[c4];
    float q0 = fminf(fmaxf(rintf(v.x / sc.x) + zp.x, 0.f), 255.f);
    float q1 = fminf(fmaxf(rintf(v.y / sc.y) + zp.y, 0.f), 255.f);
    float q2 = fminf(fmaxf(rintf(v.z / sc.z) + zp.z, 0.f), 255.f);
    float q3 = fminf(fmaxf(rintf(v.w / sc.w) + zp.w, 0.f), 255.f);
    ushort4 o;
    o.x = f2bf((q0 - zp.x) * sc.x);
    o.y = f2bf((q1 - zp.y) * sc.y);
    o.z = f2bf((q2 - zp.z) * sc.z);
    o.w = f2bf((q3 - zp.w) * sc.w);
    ((ushort4*)xq)[i4] = o;
  }
}

// ---- Stage 4+5a fused: trellis decode + FWHT over OUT bits 0..5 (H64 inner) ----
__global__ void fwht_w_inner_fused(const int* __restrict__ trellis, float* __restrict__ w) {
  __shared__ float t[64][65];
  const int ohi = blockIdx.x >> 6;
  const int it  = blockIdx.x & 63;
  const int tid = threadIdx.x;
  const float g = 0.44721359549995793f;  // 1/sqrt(5)
#pragma unroll
  for (int j = 0; j < 2; ++j) {
    int wi = j * 256 + tid;       // 0..511 : word r*8+wc
    int r = wi >> 3, wc = wi & 7;
    int word = trellis[(size_t)(ohi * 64 + r) * 512 + it * 8 + wc];
#pragma unroll
    for (int jj = 0; jj < 8; ++jj) {
      int code = (word >> (14 - 2 * jj)) & 3;
      t[r][wc * 8 + jj] = (float)(2 * code - 3) * g;
    }
  }
  for (int h = 1; h < 64; h <<= 1) {
    __syncthreads();
#pragma unroll
    for (int j = 0; j < 8; ++j) {
      int p = j * 256 + tid;   // 0..2047
      int c = p & 63, q = p >> 6;
      int rr = q & (h - 1);
      int i0 = ((q & ~(h - 1)) << 1) | rr;
      float a = t[i0][c], b = t[i0 + h][c];
      t[i0][c] = a + b;
      t[i0 + h][c] = a - b;
    }
  }
  __syncthreads();
#pragma unroll
  for (int j = 0; j < 16; ++j) {
    int e = j * 256 + tid;
    int r = e >> 6, c = e & 63;
    w[((size_t)(ohi * 64 + r)) * IN_DIM + it * 64 + c] = t[r][c];
  }
}

// Pass B: bits 6..11 (transform over ohi) + 1/64 norm + SV + group scales + bf16
__global__ void fwht_w_outer(const float* __restrict__ w, const float* __restrict__ SV,
                             const float* __restrict__ wscale, unsigned short* __restrict__ wq) {
  __shared__ float t[64][65];
  const int olo = blockIdx.x >> 6;
  const int it  = blockIdx.x & 63;
  const int tid = threadIdx.x;
#pragma unroll
  for (int j = 0; j < 16; ++j) {
    int e = j * 256 + tid;
    int r = e >> 6, c = e & 63;
    t[r][c] = w[((size_t)(r * 64 + olo)) * IN_DIM + it * 64 + c];
  }
  for (int h = 1; h < 64; h <<= 1) {
    __syncthreads();
#pragma unroll
    for (int j = 0; j < 8; ++j) {
      int p = j * 256 + tid;
      int c = p & 63, q = p >> 6;
      int rr = q & (h - 1);
      int i0 = ((q & ~(h - 1)) << 1) | rr;
      float a = t[i0][c], b = t[i0 + h][c];
      t[i0][c] = a + b;
      t[i0 + h][c] = a - b;
    }
  }
  __syncthreads();
#pragma unroll
  for (int j = 0; j < 16; ++j) {
    int e = j * 256 + tid;
    int r = e >> 6, c = e & 63;
    int o = r * 64 + olo;
    int i = it * 64 + c;
    float val = t[r][c] * 0.015625f * SV[o] * wscale[(o << 4) + (i >> 8)];
    wq[(size_t)o * IN_DIM + i] = f2bf(val);
  }
}

// ---------------- Stage 6: 256x256 8-phase bf16 GEMM (T1+T2+T3+T4+T5) ----------
// C[m,o] = sum_k A[m,k]*B[o,k].  BM=BN=256, BK=64, 8 waves (2M x 4N), 512 thr.
// LDS 128 KiB: A[2buf][2half][128r][64k], B same, bf16, XOR slot-swizzle s^=(r&7).
// Per phase: 12 ds_read_b128 (one quadrant x K=64) + 2 global_load_lds (one
// half-tile stage) + counted vmcnt + barrier + 16 MFMA in setprio(1).
__global__ __launch_bounds__(512, 2) void gemm256_kernel(
    const unsigned short* __restrict__ A, const unsigned short* __restrict__ B,
    float* __restrict__ C) {
  __shared__ __align__(16) unsigned short lds[65536];  // 128 KiB
  const int tid  = threadIdx.x;
  const int lane = tid & 63;
  const int wave = tid >> 6;
  const int wm = wave >> 2, wn = wave & 3;
  const int fr = lane & 15, kqi = lane >> 4;
  const int swz = fr & 7;   // rh&7 == fr&7 for all fragment rows

  // XCD-aware bijective swizzle (nwg=512, 512%8==0)
  const int b  = blockIdx.x;
  const int wg = (b & 7) * 64 + (b >> 3);
  const int bm = wg >> 4, bn = wg & 15;
  const int gm0 = bm * 256, gn0 = bn * 256;

  f32x4 acc[2][2][4][2] = {};  // [qm][qn][mi][ni]

  // stage one half-tile (128 rows x 64 k, 16 KiB): 2 x global_load_lds/thread.
  // LDS linear dest (lane-contiguous); source pre-swizzled: slot s = s' ^ (rh&7).
  const int F0 = tid, F1 = 512 + tid;
  const int rh0 = F0 >> 3, s0 = (F0 & 7) ^ (rh0 & 7);
  const int rh1 = F1 >> 3, s1 = (F1 & 7) ^ (rh1 & 7);
  auto stage = [&](const unsigned short* gbase, int grow0, int kcol, int ldsoff) {
    async16((void*)&lds[ldsoff + F0 * 8],
            (const void*)(gbase + (size_t)(grow0 + rh0) * IN_DIM + kcol + s0 * 8));
    async16((void*)&lds[ldsoff + F1 * 8],
            (const void*)(gbase + (size_t)(grow0 + rh1) * IN_DIM + kcol + s1 * 8));
  };

#define PHASE(QM, QN, TBUF, SGBASE, SGROW0, SKCOL, SLDSOFF, VM)                          \
  {                                                                                      \
    s16x8 af[4][2], bf[2][2];                                                            \
    const int abase = (TBUF) * 16384 + (QM) * 8192;                                      \
    const int bbase = 32768 + (TBUF) * 16384 + (QN) * 8192;                              \
    _Pragma("unroll") for (int kk = 0; kk < 2; ++kk) {                                   \
      _Pragma("unroll") for (int mi = 0; mi < 4; ++mi) {                                 \
        int rh = wm * 64 + mi * 16 + fr;                                                 \
        af[mi][kk] = *(const s16x8*)&lds[abase + rh * 64 + (((kk * 4 + kqi) ^ swz) * 8)];\
      }                                                                                  \
      _Pragma("unroll") for (int ni = 0; ni < 2; ++ni) {                                 \
        int rh = wn * 32 + ni * 16 + fr;                                                 \
        bf[ni][kk] = *(const s16x8*)&lds[bbase + rh * 64 + (((kk * 4 + kqi) ^ swz) * 8)];\
      }                                                                                  \
    }                                                                                    \
    stage(SGBASE, SGROW0, SKCOL, SLDSOFF);                                               \
    FENCE;                                                                               \
    asm volatile("s_waitcnt vmcnt(" #VM ")" ::: "memory");                               \
    __builtin_amdgcn_s_barrier();                                                        \
    FENCE;                                                                               \
    __builtin_amdgcn_s_setprio(1);                                                       \
    _Pragma("unroll") for (int kk = 0; kk < 2; ++kk)                                     \
      _Pragma("unroll") for (int mi = 0; mi < 4; ++mi)                                   \
        _Pragma("unroll") for (int ni = 0; ni < 2; ++ni)                                 \
          acc[QM][QN][mi][ni] = __builtin_amdgcn_mfma_f32_16x16x32_bf16(                 \
              af[mi][kk], bf[ni][kk], acc[QM][QN][mi][ni], 0, 0, 0);                     \
    __builtin_amdgcn_s_setprio(0);                                                       \
    FENCE;                                                                               \
    __builtin_amdgcn_s_barrier();                                                        \
    FENCE;                                                                               \
  }

  // prologue: stage T0 fully + T1 half0s; keep T1.H0 pair in flight (vmcnt(8))
  stage(A, gm0,       0, 0);       // T0.A-H0 -> buf0
  stage(B, gn0,       0, 32768);   // T0.B-H0 -> buf0
  stage(A, gm0 + 128, 0, 8192);    // T0.A-H1 -> buf0
  stage(B, gn0 + 128, 0, 40960);   // T0.B-H1 -> buf0
  stage(A, gm0,      64, 16384);   // T1.A-H0 -> buf1
  stage(B, gn0,      64, 49152);   // T1.B-H0 -> buf1
  FENCE;
  asm volatile("s_waitcnt vmcnt(8)" ::: "memory");
  __builtin_amdgcn_s_barrier();
  FENCE;

  for (int it = 0; it < 32; ++it) {
    const int k1 = ((2 * it + 1) * 64) & 4095;  // tile T+1
    const int k2 = ((2 * it + 2) * 64) & 4095;  // tile T+2 (clamped on last iter)
    const int k3 = ((2 * it + 3) * 64) & 4095;  // tile T+3 (clamped)
    PHASE(0, 0, 0, A, gm0 + 128, k1, 24576, 6);   // stage (T+1).A-H1 -> buf1
    PHASE(0, 1, 0, B, gn0 + 128, k1, 57344, 63);  // (T+1).B-H1 -> buf1
    PHASE(1, 0, 0, A, gm0,       k2, 0,     63);  // (T+2).A-H0 -> buf0
    PHASE(1, 1, 0, B, gn0,       k2, 32768, 8);   // (T+2).B-H0 -> buf0
    PHASE(0, 0, 1, A, gm0 + 128, k2, 8192,  6);   // (T+2).A-H1 -> buf0
    PHASE(0, 1, 1, B, gn0 + 128, k2, 40960, 63);  // (T+2).B-H1 -> buf0
    PHASE(1, 0, 1, A, gm0,       k3, 16384, 63);  // (T+3).A-H0 -> buf1
    PHASE(1, 1, 1, B, gn0,       k3, 49152, 8);   // (T+3).B-H0 -> buf1
  }
#undef PHASE
  asm volatile("s_waitcnt vmcnt(0)" ::: "memory");

  // epilogue: C[row, col]
  const int orow = kqi * 4;
#pragma unroll
  for (int qm = 0; qm < 2; ++qm)
#pragma unroll
    for (int qn = 0; qn < 2; ++qn)
#pragma unroll
      for (int mi = 0; mi < 4; ++mi)
#pragma unroll
        for (int ni = 0; ni < 2; ++ni) {
          const int row0 = gm0 + qm * 128 + wm * 64 + mi * 16 + orow;
          const int col  = gn0 + qn * 128 + wn * 32 + ni * 16 + fr;
          f32x4 v = acc[qm][qn][mi][ni];
#pragma unroll
          for (int r = 0; r < 4; ++r)
            C[(size_t)(row0 + r) * OUT_DIM + col] = v[r];
        }
}

// ---------------- launch ----------------
extern "C" void kernel_launch(void* const* d_in, const int* in_sizes, int n_in,
                              void* d_out, int out_size, void* d_ws, size_t ws_size,
                              hipStream_t stream) {
  const float* x      = (const float*)d_in[0];
  const float* SU     = (const float*)d_in[1];
  const float* SV     = (const float*)d_in[2];
  const float* wscale = (const float*)d_in[3];
  const int* trellis  = (const int*)d_in[4];
  float* out = (float*)d_out;

  // ws layout (96 MiB total):
  //   xq bf16 [0, 64Mi) ; wq bf16 [64Mi, 96Mi) -- min/max partials aliased into
  //   wq's region (consumed before wq is produced)
  char* ws = (char*)d_ws;
  unsigned short* xq = (unsigned short*)ws;
  unsigned short* wq = (unsigned short*)(ws + (size_t)67108864);
  float* pmin  = (float*)(ws + (size_t)67108864);
  float* pmax  = (float*)(ws + (size_t)67108864 + 524288);
  float* scale = (float*)(ws + (size_t)67108864 + 1048576);
  float* zero  = (float*)(ws + (size_t)67108864 + 1064960);

  float* xh   = out;  // reuse d_out (128 MiB) as xh scratch
  float* wdec = out;  // then (after quant consumes xh) as decoded-W scratch

  hipLaunchKernelGGL(fwht_x_kernel, dim3(M_ROWS), dim3(256), 0, stream, x, SU, xh);
  hipLaunchKernelGGL(minmax_part_kernel, dim3(512), dim3(256), 0, stream, xh, pmin, pmax);
  hipLaunchKernelGGL(minmax_fin_kernel, dim3(16), dim3(256), 0, stream, pmin, pmax, scale, zero);
  hipLaunchKernelGGL(quant_kernel, dim3(2048), dim3(256), 0, stream, xh, scale, zero, xq);
  hipLaunchKernelGGL(fwht_w_inner_fused, dim3(4096), dim3(256), 0, stream, trellis, wdec);
  hipLaunchKernelGGL(fwht_w_outer, dim3(4096), dim3(256), 0, stream, wdec, SV, wscale, wq);
  hipLaunchKernelGGL(gemm256_kernel, dim3((M_ROWS / 256) * (OUT_DIM / 256)), dim3(512), 0,
                     stream, xq, wq, out);
}

// Round 3
// 371.395 us; speedup vs baseline: 1.5793x; 1.1721x over previous
//
#include <hip/hip_runtime.h>
#include <hip/hip_bf16.h>
#include <stdint.h>

#define IN_DIM 4096
#define OUT_DIM 4096
#define M_ROWS 8192   // 4 * 2048

typedef __attribute__((ext_vector_type(8))) short s16x8;
typedef __attribute__((ext_vector_type(4))) float f32x4;

__device__ __forceinline__ unsigned short f2bf(float f) {
  uint32_t u = __float_as_uint(f);
  uint32_t r = (u + 0x7fffu + ((u >> 16) & 1u)) >> 16;  // RNE
  return (unsigned short)r;
}

__device__ __forceinline__ void async16(void* lds, const void* g) {
  __builtin_amdgcn_global_load_lds(
      (const __attribute__((address_space(1))) unsigned int*)g,
      (__attribute__((address_space(3))) unsigned int*)lds, 16, 0, 0);
}

#define FENCE asm volatile("" ::: "memory")

// in-register H16 (4 radix-2 stages, all indices compile-time)
__device__ __forceinline__ void h16(float (&v)[16]) {
#pragma unroll
  for (int h = 1; h < 16; h <<= 1) {
#pragma unroll
    for (int g = 0; g < 8; ++g) {
      int r = g & (h - 1);
      int i0 = ((g & ~(h - 1)) << 1) | r;
      float a = v[i0], b = v[i0 + h];
      v[i0] = a + b;
      v[i0 + h] = a - b;
    }
  }
}

// ---------------- Stage 1: xh = fwht(x * SU) = (H16 (x) H16 (x) H16) ----------
// n = a*256 + b*16 + c. Three in-register H16 passes + 2 padded LDS exchanges.
__global__ void fwht_x_kernel(const float* __restrict__ x, const float* __restrict__ SU,
                              float* __restrict__ xh) {
  __shared__ float s[4352];  // padded: addr(i) = i + (i>>4)
  const int row = blockIdx.x;
  const int t = threadIdx.x;
  float v[16];
  const float4* xr  = (const float4*)(x + (size_t)row * IN_DIM);
  const float4* su4 = (const float4*)SU;
#pragma unroll
  for (int q = 0; q < 4; ++q) {
    float4 a = xr[t * 4 + q], sv = su4[t * 4 + q];
    v[q * 4 + 0] = a.x * sv.x;
    v[q * 4 + 1] = a.y * sv.y;
    v[q * 4 + 2] = a.z * sv.z;
    v[q * 4 + 3] = a.w * sv.w;
  }
  h16(v);  // over c (thread owns a=t>>4, b=t&15)
#pragma unroll
  for (int c = 0; c < 16; ++c) {
    int i = t * 16 + c;
    s[i + (i >> 4)] = v[c];
  }
  __syncthreads();
  const int A = t >> 4, C = t & 15;
#pragma unroll
  for (int b = 0; b < 16; ++b) {
    int i = A * 256 + b * 16 + C;
    v[b] = s[i + (i >> 4)];
  }
  h16(v);  // over b
  __syncthreads();
#pragma unroll
  for (int b = 0; b < 16; ++b) {
    int i = A * 256 + b * 16 + C;
    s[i + (i >> 4)] = v[b];
  }
  __syncthreads();
#pragma unroll
  for (int a = 0; a < 16; ++a) {
    int i = a * 256 + t;  // B = t>>4, C2 = t&15 -> B*16+C2 = t
    v[a] = s[i + (i >> 4)];
  }
  h16(v);  // over a
  float* orow = xh + (size_t)row * IN_DIM;
#pragma unroll
  for (int a = 0; a < 16; ++a) orow[a * 256 + t] = v[a] * 0.015625f;
}

// ---------------- Stage 2: per-channel min/max (two-stage) ----------------
__global__ void minmax_part_kernel(const float* __restrict__ xh,
                                   float* __restrict__ pmin, float* __restrict__ pmax) {
  const int rc = blockIdx.x >> 4;
  const int cb = blockIdx.x & 15;
  const int ch = cb * 256 + threadIdx.x;
  float mn = 3.4e38f, mx = -3.4e38f;
  const float* base = xh + (size_t)rc * 256 * IN_DIM + ch;
  for (int r = 0; r < 256; ++r) {
    float v = base[(size_t)r * IN_DIM];
    mn = fminf(mn, v);
    mx = fmaxf(mx, v);
  }
  pmin[rc * IN_DIM + ch] = mn;
  pmax[rc * IN_DIM + ch] = mx;
}

__global__ void minmax_fin_kernel(const float* __restrict__ pmin, const float* __restrict__ pmax,
                                  float* __restrict__ scale, float* __restrict__ zero) {
  int ch = blockIdx.x * 256 + threadIdx.x;
  float mn = 3.4e38f, mx = -3.4e38f;
  for (int rc = 0; rc < 32; ++rc) {
    mn = fminf(mn, pmin[rc * IN_DIM + ch]);
    mx = fmaxf(mx, pmax[rc * IN_DIM + ch]);
  }
  float sc = fmaxf((mx - mn) / 255.0f, 1e-8f);
  float zp = rintf(-mn / sc);
  scale[ch] = sc;
  zero[ch] = zp;
}

// ---------------- Stage 3: fake-quant + bf16 cast ----------------
__global__ void quant_kernel(const float* __restrict__ xh, const float* __restrict__ scale,
                             const float* __restrict__ zero, unsigned short* __restrict__ xq) {
  const int total4 = M_ROWS * IN_DIM / 4;
  for (int i4 = blockIdx.x * blockDim.x + threadIdx.x; i4 < total4;
       i4 += gridDim.x * blockDim.x) {
    int c4 = i4 & (IN_DIM / 4 - 1);
    float4 v  = ((const float4*)xh)[i4];
    float4 sc = ((const float4*)scale)[c4];
    float4 zp = ((const float4*)zero)[c4];
    float q0 = fminf(fmaxf(rintf(v.x / sc.x) + zp.x, 0.f), 255.f);
    float q1 = fminf(fmaxf(rintf(v.y / sc.y) + zp.y, 0.f), 255.f);
    float q2 = fminf(fmaxf(rintf(v.z / sc.z) + zp.z, 0.f), 255.f);
    float q3 = fminf(fmaxf(rintf(v.w / sc.w) + zp.w, 0.f), 255.f);
    ushort4 o;
    o.x = f2bf((q0 - zp.x) * sc.x);
    o.y = f2bf((q1 - zp.y) * sc.y);
    o.z = f2bf((q2 - zp.z) * sc.z);
    o.w = f2bf((q3 - zp.w) * sc.w);
    ((ushort4*)xq)[i4] = o;
  }
}

// radix-4 butterfly macro over t[64][65] columns
#define W_RADIX4(TARR)                                                     \
  for (int h = 1; h < 64; h <<= 2) {                                       \
    __syncthreads();                                                       \
    _Pragma("unroll") for (int j = 0; j < 4; ++j) {                        \
      int g = j * 256 + tid;                                               \
      int c = g & 63, u = g >> 6;                                          \
      int r = u & (h - 1);                                                 \
      int i0 = ((u & ~(h - 1)) << 2) | r;                                  \
      float a = TARR[i0][c], b2 = TARR[i0 + h][c];                         \
      float c2 = TARR[i0 + 2 * h][c], d = TARR[i0 + 3 * h][c];             \
      float y0 = a + b2, y1 = a - b2, y2 = c2 + d, y3 = c2 - d;            \
      TARR[i0][c] = y0 + y2;                                               \
      TARR[i0 + h][c] = y1 + y3;                                           \
      TARR[i0 + 2 * h][c] = y0 - y2;                                       \
      TARR[i0 + 3 * h][c] = y1 - y3;                                       \
    }                                                                      \
  }                                                                        \
  __syncthreads();

// ---- Stage 4+5a fused: trellis decode + FWHT over OUT bits 0..5 (H64 inner) ----
__global__ void fwht_w_inner_fused(const int* __restrict__ trellis, float* __restrict__ w) {
  __shared__ float t[64][65];
  const int ohi = blockIdx.x >> 6;
  const int it  = blockIdx.x & 63;
  const int tid = threadIdx.x;
  const float g = 0.44721359549995793f;  // 1/sqrt(5)
#pragma unroll
  for (int j = 0; j < 2; ++j) {
    int wi = j * 256 + tid;
    int r = wi >> 3, wc = wi & 7;
    int word = trellis[(size_t)(ohi * 64 + r) * 512 + it * 8 + wc];
#pragma unroll
    for (int jj = 0; jj < 8; ++jj) {
      int code = (word >> (14 - 2 * jj)) & 3;
      t[r][wc * 8 + jj] = (float)(2 * code - 3) * g;
    }
  }
  W_RADIX4(t)
#pragma unroll
  for (int j = 0; j < 16; ++j) {
    int e = j * 256 + tid;
    int r = e >> 6, c = e & 63;
    w[((size_t)(ohi * 64 + r)) * IN_DIM + it * 64 + c] = t[r][c];
  }
}

// Pass B: bits 6..11 + 1/64 norm + SV + group scales + bf16
__global__ void fwht_w_outer(const float* __restrict__ w, const float* __restrict__ SV,
                             const float* __restrict__ wscale, unsigned short* __restrict__ wq) {
  __shared__ float t[64][65];
  const int olo = blockIdx.x >> 6;
  const int it  = blockIdx.x & 63;
  const int tid = threadIdx.x;
#pragma unroll
  for (int j = 0; j < 16; ++j) {
    int e = j * 256 + tid;
    int r = e >> 6, c = e & 63;
    t[r][c] = w[((size_t)(r * 64 + olo)) * IN_DIM + it * 64 + c];
  }
  W_RADIX4(t)
#pragma unroll
  for (int j = 0; j < 16; ++j) {
    int e = j * 256 + tid;
    int r = e >> 6, c = e & 63;
    int o = r * 64 + olo;
    int i = it * 64 + c;
    float val = t[r][c] * 0.015625f * SV[o] * wscale[(o << 4) + (i >> 8)];
    wq[(size_t)o * IN_DIM + i] = f2bf(val);
  }
}

// ---------------- Stage 6: 256x256 8-phase bf16 GEMM (dedup'd ds_reads) --------
// Per K-tile: P1 reads af(QM0)+bf(QN0), P2 reads bf(QN1), P3 reads af(QM1),
// P4 reads nothing; bf held in regs across all 4 phases. 24 ds_read_b128 per
// wave per K-tile (was 48). Stage schedule + vmcnt identical to prior round.
__global__ __launch_bounds__(512, 2) void gemm256_kernel(
    const unsigned short* __restrict__ A, const unsigned short* __restrict__ B,
    float* __restrict__ C) {
  __shared__ __align__(16) unsigned short lds[65536];  // 128 KiB
  const int tid  = threadIdx.x;
  const int lane = tid & 63;
  const int wave = tid >> 6;
  const int wm = wave >> 2, wn = wave & 3;
  const int fr = lane & 15, kqi = lane >> 4;
  const int swz = fr & 7;

  // XCD-aware bijective swizzle (nwg=512, 512%8==0)
  const int b  = blockIdx.x;
  const int wg = (b & 7) * 64 + (b >> 3);
  const int bm = wg >> 4, bn = wg & 15;
  const int gm0 = bm * 256, gn0 = bn * 256;

  f32x4 acc[2][2][4][2] = {};  // [qm][qn][mi][ni]
  s16x8 af[4][2];              // current QM quadrant [mi][kk]
  s16x8 bf[2][2][2];           // [QN][ni][kk], both QN held across the K-tile

  const int F0 = tid, F1 = 512 + tid;
  const int rh0 = F0 >> 3, s0 = (F0 & 7) ^ (rh0 & 7);
  const int rh1 = F1 >> 3, s1 = (F1 & 7) ^ (rh1 & 7);
  auto stage = [&](const unsigned short* gbase, int grow0, int kcol, int ldsoff) {
    async16((void*)&lds[ldsoff + F0 * 8],
            (const void*)(gbase + (size_t)(grow0 + rh0) * IN_DIM + kcol + s0 * 8));
    async16((void*)&lds[ldsoff + F1 * 8],
            (const void*)(gbase + (size_t)(grow0 + rh1) * IN_DIM + kcol + s1 * 8));
  };

#define READ_AF(QM, TBUF)                                                                \
  {                                                                                      \
    const int abase = (TBUF) * 16384 + (QM) * 8192;                                      \
    _Pragma("unroll") for (int kk = 0; kk < 2; ++kk)                                     \
      _Pragma("unroll") for (int mi = 0; mi < 4; ++mi) {                                 \
        int rh = wm * 64 + mi * 16 + fr;                                                 \
        af[mi][kk] = *(const s16x8*)&lds[abase + rh * 64 + (((kk * 4 + kqi) ^ swz) * 8)];\
      }                                                                                  \
  }
#define READ_BF(QN, TBUF)                                                                \
  {                                                                                      \
    const int bbase = 32768 + (TBUF) * 16384 + (QN) * 8192;                              \
    _Pragma("unroll") for (int kk = 0; kk < 2; ++kk)                                     \
      _Pragma("unroll") for (int ni = 0; ni < 2; ++ni) {                                 \
        int rh = wn * 32 + ni * 16 + fr;                                                 \
        bf[QN][ni][kk] =                                                                 \
            *(const s16x8*)&lds[bbase + rh * 64 + (((kk * 4 + kqi) ^ swz) * 8)];         \
      }                                                                                  \
  }
#define ENDPHASE(QM, QN, SGBASE, SGROW0, SKCOL, SLDSOFF, VM)                             \
  {                                                                                      \
    stage(SGBASE, SGROW0, SKCOL, SLDSOFF);                                               \
    FENCE;                                                                               \
    asm volatile("s_waitcnt vmcnt(" #VM ")" ::: "memory");                               \
    __builtin_amdgcn_s_barrier();                                                        \
    FENCE;                                                                               \
    __builtin_amdgcn_s_setprio(1);                                                       \
    _Pragma("unroll") for (int kk = 0; kk < 2; ++kk)                                     \
      _Pragma("unroll") for (int mi = 0; mi < 4; ++mi)                                   \
        _Pragma("unroll") for (int ni = 0; ni < 2; ++ni)                                 \
          acc[QM][QN][mi][ni] = __builtin_amdgcn_mfma_f32_16x16x32_bf16(                 \
              af[mi][kk], bf[QN][ni][kk], acc[QM][QN][mi][ni], 0, 0, 0);                 \
    __builtin_amdgcn_s_setprio(0);                                                       \
    FENCE;                                                                               \
    __builtin_amdgcn_s_barrier();                                                        \
    FENCE;                                                                               \
  }

  // prologue: stage T0 fully + T1 half0s; keep T1.H0 pair in flight
  stage(A, gm0,       0, 0);       // T0.A-H0 -> buf0
  stage(B, gn0,       0, 32768);   // T0.B-H0 -> buf0
  stage(A, gm0 + 128, 0, 8192);    // T0.A-H1 -> buf0
  stage(B, gn0 + 128, 0, 40960);   // T0.B-H1 -> buf0
  stage(A, gm0,      64, 16384);   // T1.A-H0 -> buf1
  stage(B, gn0,      64, 49152);   // T1.B-H0 -> buf1
  FENCE;
  asm volatile("s_waitcnt vmcnt(8)" ::: "memory");
  __builtin_amdgcn_s_barrier();
  FENCE;

  for (int it = 0; it < 32; ++it) {
    const int k1 = ((2 * it + 1) * 64) & 4095;
    const int k2 = ((2 * it + 2) * 64) & 4095;
    const int k3 = ((2 * it + 3) * 64) & 4095;
    // ---- K-tile in buf0 ----
    READ_AF(0, 0) READ_BF(0, 0)
    ENDPHASE(0, 0, A, gm0 + 128, k1, 24576, 6)   // stage (T+1).A-H1 -> buf1
    READ_BF(1, 0)
    ENDPHASE(0, 1, B, gn0 + 128, k1, 57344, 63)  // (T+1).B-H1 -> buf1
    READ_AF(1, 0)
    ENDPHASE(1, 1, A, gm0,       k2, 0,     63)  // (T+2).A-H0 -> buf0
    ENDPHASE(1, 0, B, gn0,       k2, 32768, 8)   // (T+2).B-H0 -> buf0
    // ---- K-tile in buf1 ----
    READ_AF(0, 1) READ_BF(0, 1)
    ENDPHASE(0, 0, A, gm0 + 128, k2, 8192,  6)   // (T+2).A-H1 -> buf0
    READ_BF(1, 1)
    ENDPHASE(0, 1, B, gn0 + 128, k2, 40960, 63)  // (T+2).B-H1 -> buf0
    READ_AF(1, 1)
    ENDPHASE(1, 1, A, gm0,       k3, 16384, 63)  // (T+3).A-H0 -> buf1
    ENDPHASE(1, 0, B, gn0,       k3, 49152, 8)   // (T+3).B-H0 -> buf1
  }
#undef ENDPHASE
#undef READ_AF
#undef READ_BF
  asm volatile("s_waitcnt vmcnt(0)" ::: "memory");

  // epilogue
  const int orow = kqi * 4;
#pragma unroll
  for (int qm = 0; qm < 2; ++qm)
#pragma unroll
    for (int qn = 0; qn < 2; ++qn)
#pragma unroll
      for (int mi = 0; mi < 4; ++mi)
#pragma unroll
        for (int ni = 0; ni < 2; ++ni) {
          const int row0 = gm0 + qm * 128 + wm * 64 + mi * 16 + orow;
          const int col  = gn0 + qn * 128 + wn * 32 + ni * 16 + fr;
          f32x4 v = acc[qm][qn][mi][ni];
#pragma unroll
          for (int r = 0; r < 4; ++r)
            C[(size_t)(row0 + r) * OUT_DIM + col] = v[r];
        }
}

// ---------------- launch ----------------
extern "C" void kernel_launch(void* const* d_in, const int* in_sizes, int n_in,
                              void* d_out, int out_size, void* d_ws, size_t ws_size,
                              hipStream_t stream) {
  const float* x      = (const float*)d_in[0];
  const float* SU     = (const float*)d_in[1];
  const float* SV     = (const float*)d_in[2];
  const float* wscale = (const float*)d_in[3];
  const int* trellis  = (const int*)d_in[4];
  float* out = (float*)d_out;

  char* ws = (char*)d_ws;
  unsigned short* xq = (unsigned short*)ws;
  unsigned short* wq = (unsigned short*)(ws + (size_t)67108864);
  float* pmin  = (float*)(ws + (size_t)67108864);
  float* pmax  = (float*)(ws + (size_t)67108864 + 524288);
  float* scale = (float*)(ws + (size_t)67108864 + 1048576);
  float* zero  = (float*)(ws + (size_t)67108864 + 1064960);

  float* xh   = out;  // reuse d_out as xh scratch
  float* wdec = out;  // then as decoded-W scratch

  hipLaunchKernelGGL(fwht_x_kernel, dim3(M_ROWS), dim3(256), 0, stream, x, SU, xh);
  hipLaunchKernelGGL(minmax_part_kernel, dim3(512), dim3(256), 0, stream, xh, pmin, pmax);
  hipLaunchKernelGGL(minmax_fin_kernel, dim3(16), dim3(256), 0, stream, pmin, pmax, scale, zero);
  hipLaunchKernelGGL(quant_kernel, dim3(2048), dim3(256), 0, stream, xh, scale, zero, xq);
  hipLaunchKernelGGL(fwht_w_inner_fused, dim3(4096), dim3(256), 0, stream, trellis, wdec);
  hipLaunchKernelGGL(fwht_w_outer, dim3(4096), dim3(256), 0, stream, wdec, SV, wscale, wq);
  hipLaunchKernelGGL(gemm256_kernel, dim3((M_ROWS / 256) * (OUT_DIM / 256)), dim3(512), 0,
                     stream, xq, wq, out);
}